// Round 6
// baseline (386.679 us; speedup 1.0000x reference)
//
#include <hip/hip_runtime.h>

#define DEVFN __device__ __forceinline__

typedef __attribute__((ext_vector_type(4))) float f32x4;
typedef __attribute__((ext_vector_type(8))) short short8;
typedef __attribute__((ext_vector_type(4))) unsigned int uint4v;
typedef __attribute__((ext_vector_type(8))) unsigned short ushort8;

constexpr int CB = 32;
constexpr int CS = 2048;
constexpr int CD = 1024;
constexpr int CU = 1024;
constexpr int CM = CB * CS;   // 65536

DEVFN unsigned f2bf_u(float f) {
    unsigned u = __float_as_uint(f);
    return (u + 0x7FFFu + ((u >> 16) & 1u)) >> 16;   // RNE f32->bf16
}
DEVFN unsigned f2bf_pack(float lo, float hi) {
    return f2bf_u(lo) | (f2bf_u(hi) << 16);
}
DEVFN short8 cvt8(f32x4 a, f32x4 b) {
    uint4v p;
    p[0] = f2bf_pack(a[0], a[1]);
    p[1] = f2bf_pack(a[2], a[3]);
    p[2] = f2bf_pack(b[0], b[1]);
    p[3] = f2bf_pack(b[2], b[3]);
    return __builtin_bit_cast(short8, p);
}
DEVFN float tanh_fast(float x) {
    float e = exp2f(x * 2.885390081777927f);
    return 1.0f - 2.0f * __builtin_amdgcn_rcpf(e + 1.0f);
}

// ---- bias = b1 + b2 + q@W2, two-stage split-D ----
__global__ void k_bias1(const float* __restrict__ q, const float* __restrict__ W2,
                        float* __restrict__ bpart) {
    int dc = blockIdx.x, b = blockIdx.y;   // 8 x 32
    int t = threadIdx.x;                    // 256
    __shared__ float qs[128];
    if (t < 128) qs[t] = q[b * CD + dc * 128 + t];
    __syncthreads();
    float acc0 = 0.f, acc1 = 0.f, acc2 = 0.f, acc3 = 0.f;
    const float* w2 = W2 + (size_t)(dc * 128) * CU + t;
#pragma unroll 4
    for (int d = 0; d < 128; ++d) {
        float qv = qs[d];
        const float* r = w2 + (size_t)d * CU;
        acc0 += qv * r[0];
        acc1 += qv * r[256];
        acc2 += qv * r[512];
        acc3 += qv * r[768];
    }
    float* o = bpart + (size_t)(b * 8 + dc) * CU + t;
    o[0] = acc0; o[256] = acc1; o[512] = acc2; o[768] = acc3;
}

__global__ void k_bias2(const float* __restrict__ bpart, const float* __restrict__ b1,
                        const float* __restrict__ b2, float* __restrict__ bias) {
    int idx = blockIdx.x * 256 + threadIdx.x;   // 32768
    int b = idx >> 10, u = idx & 1023;
    float s = b1[u] + b2[u];
#pragma unroll
    for (int dc = 0; dc < 8; ++dc) s += bpart[(size_t)(b * 8 + dc) * CU + u];
    bias[idx] = s;
}

// ---- pack W1[D][U] f32 -> bf16, MFMA-B fragment-linear tiles ----
// idx = (kt*4+ut)*8192 + ub*512 + l*8 + j ; d = kt*32 + (l>>4)*8 + j ; u = ut*256 + ub*16 + (l&15)
__global__ void k_packW1(const float* __restrict__ W1, unsigned short* __restrict__ W1p) {
    int tid = blockIdx.x * 256 + threadIdx.x;   // 131072 threads, 8 elems each
    int o8  = tid * 8;
    int l   = (o8 >> 3) & 63;
    int ub  = (o8 >> 9) & 15;
    int ut  = (o8 >> 13) & 3;
    int kt  = o8 >> 15;
    int u  = ut * 256 + ub * 16 + (l & 15);
    int d0 = kt * 32 + (l >> 4) * 8;
    ushort8 v;
#pragma unroll
    for (int j = 0; j < 8; ++j)
        v[j] = (unsigned short)f2bf_u(W1[(size_t)(d0 + j) * CU + u]);
    *(ushort8*)(W1p + o8) = v;
}

// ---- fused score GEMM v3: BM=128 x U_blk=512, 8 waves (each 128 rows x 64 cols).
// A: chunked LDS dbuf (2 x 64KB bf16, 8 K-steps/chunk), drip-staged via regs (T14),
//    XOR ^s slot swizzle. ONE barrier per 8 steps.
// B: global->reg dbuf, full-step prefetch. acc[8][4]=128 regs.
__global__ __launch_bounds__(512, 2) void k_score(
    const float* __restrict__ values, const unsigned short* __restrict__ W1p,
    const float* __restrict__ bias, const float* __restrict__ V,
    float* __restrict__ score2) {
    __shared__ __align__(16) char smem[131072];

    const int t = threadIdx.x;
    const int w = t >> 6, l = t & 63;
    const int bid = blockIdx.x;
    const int L = (bid >> 3) + (bid & 7) * 128;   // XCD-paired logical index
    const int xt = L >> 1, uc = L & 1;
    const int m0 = xt * 128;
    const int bb = m0 >> 11;                      // batch (128 divides S)

    // stage: per step s, thread t loads row m0 + s*16 + (t>>5), k-cell (t&31)*8 (8 f32)
    const float* sBase = values + (size_t)(m0 + (t >> 5)) * CD + (t & 31) * 8;
    // ds_write: s2 = cell>>2 (k-step), khi = cell&3, slot = (r0 + khi*16) ^ s2
    const int s2w = (t & 31) >> 2;
    const int wrBase = s2w * 8192 + ((((t >> 5) + (t & 3) * 16)) ^ s2w) * 16;
    const int lB = l * 16;
    // B: wave w covers cols uc*512 + w*64; frag jj -> 1KB coalesced
    const unsigned short* bSrc = W1p + (size_t)(2 * uc + (w >> 2)) * 8192 + (w & 3) * 2048 + l * 8;

    short8 bF0[4], bF1[4];
    f32x4 stgA0, stgA1, stgB0, stgB1;

    // ---- prologue: stage chunk 0 (f32 -> bf16 -> LDS slot 0), load B(0) ----
    {
        f32x4 pa[8], pb[8];
#pragma unroll
        for (int s = 0; s < 8; ++s) {
            pa[s] = *(const f32x4*)(sBase + s * 16384);
            pb[s] = *(const f32x4*)(sBase + s * 16384 + 4);
        }
#pragma unroll
        for (int s = 0; s < 8; ++s)
            *(short8*)(smem + wrBase + s * 1024) = cvt8(pa[s], pb[s]);
    }
#pragma unroll
    for (int jj = 0; jj < 4; ++jj)
        bF0[jj] = *(const short8*)(bSrc + jj * 512);
    asm volatile("s_waitcnt lgkmcnt(0)" ::: "memory");
    asm volatile("s_barrier" ::: "memory");

    f32x4 acc[8][4];
#pragma unroll
    for (int i = 0; i < 8; ++i)
#pragma unroll
        for (int j = 0; j < 4; ++j) acc[i][j] = f32x4{0.f, 0.f, 0.f, 0.f};

#pragma unroll
    for (int cc = 0; cc < 4; ++cc) {
        const int h = cc & 1;
#pragma unroll
        for (int s = 0; s < 8; ++s) {
            const int kt = cc * 8 + s;
            // 1. B prefetch for kt+1 into other parity slot
            if (kt < 31) {
                const unsigned short* bs = bSrc + (size_t)(kt + 1) * 32768;
                if ((s & 1) == 0) {
#pragma unroll
                    for (int jj = 0; jj < 4; ++jj) bF1[jj] = *(const short8*)(bs + jj * 512);
                } else {
#pragma unroll
                    for (int jj = 0; jj < 4; ++jj) bF0[jj] = *(const short8*)(bs + jj * 512);
                }
            }
            // 2. A fragment reads (conflict-free swizzled)
            short8 aF[8];
#pragma unroll
            for (int i = 0; i < 8; ++i)
                aF[i] = *(const short8*)(smem + h * 65536 + s * 8192 + i * 1024 + (lB ^ (s * 16)));
            // 3. write stage-portion s-2, then 4. issue stage loads portion s (chunk cc+1)
            if (cc < 3) {
                if (s >= 2) {
                    if ((s & 1) == 0)
                        *(short8*)(smem + (h ^ 1) * 65536 + wrBase + (s - 2) * 1024) = cvt8(stgA0, stgA1);
                    else
                        *(short8*)(smem + (h ^ 1) * 65536 + wrBase + (s - 2) * 1024) = cvt8(stgB0, stgB1);
                }
                const float* sp = sBase + (cc + 1) * 256 + s * 16384;
                if ((s & 1) == 0) { stgA0 = *(const f32x4*)sp; stgA1 = *(const f32x4*)(sp + 4); }
                else              { stgB0 = *(const f32x4*)sp; stgB1 = *(const f32x4*)(sp + 4); }
            }
            // 5. MFMA 8x4
            __builtin_amdgcn_s_setprio(1);
            if ((s & 1) == 0) {
#pragma unroll
                for (int j = 0; j < 4; ++j)
#pragma unroll
                    for (int i = 0; i < 8; ++i)
                        acc[i][j] = __builtin_amdgcn_mfma_f32_16x16x32_bf16(
                            aF[i], bF0[j], acc[i][j], 0, 0, 0);
            } else {
#pragma unroll
                for (int j = 0; j < 4; ++j)
#pragma unroll
                    for (int i = 0; i < 8; ++i)
                        acc[i][j] = __builtin_amdgcn_mfma_f32_16x16x32_bf16(
                            aF[i], bF1[j], acc[i][j], 0, 0, 0);
            }
            __builtin_amdgcn_s_setprio(0);
        }
        if (cc < 3) {
            // tail portions 6,7 then chunk barrier (the only sync per 8 steps)
            *(short8*)(smem + ((cc & 1) ^ 1) * 65536 + wrBase + 6 * 1024) = cvt8(stgA0, stgA1);
            *(short8*)(smem + ((cc & 1) ^ 1) * 65536 + wrBase + 7 * 1024) = cvt8(stgB0, stgB1);
            asm volatile("s_waitcnt lgkmcnt(0)" ::: "memory");
            asm volatile("s_barrier" ::: "memory");
        }
    }

    // ---- epilogue: partial score over this wave's 64 cols ----
    float part[8][4];
#pragma unroll
    for (int i = 0; i < 8; ++i)
#pragma unroll
        for (int rr = 0; rr < 4; ++rr) part[i][rr] = 0.f;

#pragma unroll
    for (int j = 0; j < 4; ++j) {
        const int col = uc * 512 + w * 64 + j * 16 + (l & 15);
        const float vv = V[col];
        const float bz = bias[bb * CU + col];
#pragma unroll
        for (int i = 0; i < 8; ++i)
#pragma unroll
            for (int rr = 0; rr < 4; ++rr)
                part[i][rr] += vv * tanh_fast(acc[i][j][rr] + bz);
    }

    float* red = (float*)smem;   // 4KB in slot0 area (chunk2 reads done since cc=2 barrier)
#pragma unroll
    for (int i = 0; i < 8; ++i)
#pragma unroll
        for (int rr = 0; rr < 4; ++rr) {
            float v = part[i][rr];
            v += __shfl_xor(v, 1);
            v += __shfl_xor(v, 2);
            v += __shfl_xor(v, 4);
            v += __shfl_xor(v, 8);
            if ((l & 15) == 0)
                red[w * 128 + i * 16 + (l >> 4) * 4 + rr] = v;
        }
    __syncthreads();
    if (t < 128) {
        float sv = 0.f;
#pragma unroll
        for (int ww = 0; ww < 8; ++ww) sv += red[ww * 128 + t];
        score2[(size_t)uc * CM + m0 + t] = sv;
    }
}

// ---- softmax over S per batch; sums the 2 u-chunk slices ----
__global__ void k_softmax(const float* __restrict__ score2, float* __restrict__ wts) {
    int b = blockIdx.x, t = threadIdx.x;   // 1024 threads
    int i0 = b * CS + t, i1 = i0 + 1024;
    float s0 = score2[i0] + score2[CM + i0];
    float s1 = score2[i1] + score2[CM + i1];
    __shared__ float red[16];
    int wv = t >> 6, ln = t & 63;
    float m = fmaxf(s0, s1);
#pragma unroll
    for (int o = 32; o >= 1; o >>= 1) m = fmaxf(m, __shfl_xor(m, o));
    if (ln == 0) red[wv] = m;
    __syncthreads();
    float M = red[0];
#pragma unroll
    for (int k = 1; k < 16; ++k) M = fmaxf(M, red[k]);
    float e0 = __expf(s0 - M), e1 = __expf(s1 - M);
    float sm = e0 + e1;
#pragma unroll
    for (int o = 32; o >= 1; o >>= 1) sm += __shfl_xor(sm, o);
    __syncthreads();
    if (ln == 0) red[wv] = sm;
    __syncthreads();
    float T = 0.f;
#pragma unroll
    for (int k = 0; k < 16; ++k) T += red[k];
    float inv = 1.0f / T;
    wts[i0] = e0 * inv;
    wts[i1] = e1 * inv;
}

// ---- context ----
__global__ void k_ctx_part(const float* __restrict__ values, const float* __restrict__ wts,
                           float* __restrict__ part) {
    int b = blockIdx.y, sc = blockIdx.x;   // 32 x 32
    int t = threadIdx.x;                    // 256, float4 each -> full D
    const float* vb = values + ((size_t)b * CS + sc * 64) * CD + t * 4;
    const float* wb = wts + b * CS + sc * 64;
    f32x4 a = {0.f, 0.f, 0.f, 0.f};
#pragma unroll 8
    for (int s = 0; s < 64; ++s) {
        float wgt = wb[s];
        f32x4 v = *(const f32x4*)(vb + (size_t)s * CD);
        a += v * wgt;
    }
    *(f32x4*)(part + (size_t)(b * 32 + sc) * CD + t * 4) = a;
}

__global__ void k_ctx_red(const float* __restrict__ part, float* __restrict__ ctx) {
    int idx = blockIdx.x * 256 + threadIdx.x;   // 32768
    int b = idx >> 10, d = idx & 1023;
    float s = 0.f;
#pragma unroll 8
    for (int c = 0; c < 32; ++c) s += part[(size_t)(b * 32 + c) * CD + d];
    ctx[idx] = s;
}

extern "C" void kernel_launch(void* const* d_in, const int* in_sizes, int n_in,
                              void* d_out, int out_size, void* d_ws, size_t ws_size,
                              hipStream_t stream) {
    const float* query  = (const float*)d_in[0];
    const float* values = (const float*)d_in[1];
    const float* W1     = (const float*)d_in[2];
    const float* b1     = (const float*)d_in[3];
    const float* W2     = (const float*)d_in[4];
    const float* b2     = (const float*)d_in[5];
    const float* V      = (const float*)d_in[6];
    // d_in[7] = bV: softmax shift-invariant, score not an output -> unused

    float* out = (float*)d_out;
    float* ctx = out;            // [32][1024]
    float* wts = out + 32768;    // [32][2048]

    char* ws = (char*)d_ws;
    float*          score2 = (float*)ws;                                       // 512 KB (1 MB reserved)
    float*          bias   = (float*)(ws + (1 << 20));                         // 128 KB
    unsigned short* W1p    = (unsigned short*)(ws + (1 << 20) + (1 << 17));    // 2 MB
    float*          part   = (float*)(ws + (1 << 20) + (1 << 17) + (1 << 21)); // 4 MB
    float*          bpart  = part;   // 1 MB, consumed before k_ctx_part

    k_bias1<<<dim3(8, 32), 256, 0, stream>>>(query, W2, bpart);
    k_bias2<<<128, 256, 0, stream>>>(bpart, b1, b2, bias);
    k_packW1<<<512, 256, 0, stream>>>(W1, W1p);
    k_score<<<1024, 512, 0, stream>>>(values, W1p, bias, V, score2);
    k_softmax<<<32, 1024, 0, stream>>>(score2, wts);
    k_ctx_part<<<dim3(32, 32), 256, 0, stream>>>(values, wts, part);
    k_ctx_red<<<128, 256, 0, stream>>>(part, ctx);
}

// Round 7
// 248.022 us; speedup vs baseline: 1.5590x; 1.5590x over previous
//
#include <hip/hip_runtime.h>

#define DEVFN __device__ __forceinline__

typedef __attribute__((ext_vector_type(4))) float f32x4;
typedef __attribute__((ext_vector_type(8))) short short8;
typedef __attribute__((ext_vector_type(4))) unsigned int uint4v;
typedef __attribute__((ext_vector_type(8))) unsigned short ushort8;

constexpr int CB = 32;
constexpr int CS = 2048;
constexpr int CD = 1024;
constexpr int CU = 1024;
constexpr int CM = CB * CS;   // 65536

DEVFN unsigned f2bf_u(float f) {
    unsigned u = __float_as_uint(f);
    return (u + 0x7FFFu + ((u >> 16) & 1u)) >> 16;   // RNE f32->bf16
}
DEVFN unsigned f2bf_pack(float lo, float hi) {
    return f2bf_u(lo) | (f2bf_u(hi) << 16);
}
DEVFN short8 cvt8(f32x4 a, f32x4 b) {
    uint4v p;
    p[0] = f2bf_pack(a[0], a[1]);
    p[1] = f2bf_pack(a[2], a[3]);
    p[2] = f2bf_pack(b[0], b[1]);
    p[3] = f2bf_pack(b[2], b[3]);
    return __builtin_bit_cast(short8, p);
}
DEVFN float tanh_fast(float x) {
    float e = exp2f(x * 2.885390081777927f);
    return 1.0f - 2.0f * __builtin_amdgcn_rcpf(e + 1.0f);
}

// ---- bias = b1 + b2 + q@W2, two-stage split-D ----
__global__ void k_bias1(const float* __restrict__ q, const float* __restrict__ W2,
                        float* __restrict__ bpart) {
    int dc = blockIdx.x, b = blockIdx.y;   // 8 x 32
    int t = threadIdx.x;                    // 256
    __shared__ float qs[128];
    if (t < 128) qs[t] = q[b * CD + dc * 128 + t];
    __syncthreads();
    float acc0 = 0.f, acc1 = 0.f, acc2 = 0.f, acc3 = 0.f;
    const float* w2 = W2 + (size_t)(dc * 128) * CU + t;
#pragma unroll 4
    for (int d = 0; d < 128; ++d) {
        float qv = qs[d];
        const float* r = w2 + (size_t)d * CU;
        acc0 += qv * r[0];
        acc1 += qv * r[256];
        acc2 += qv * r[512];
        acc3 += qv * r[768];
    }
    float* o = bpart + (size_t)(b * 8 + dc) * CU + t;
    o[0] = acc0; o[256] = acc1; o[512] = acc2; o[768] = acc3;
}

__global__ void k_bias2(const float* __restrict__ bpart, const float* __restrict__ b1,
                        const float* __restrict__ b2, float* __restrict__ bias) {
    int idx = blockIdx.x * 256 + threadIdx.x;   // 32768
    int b = idx >> 10, u = idx & 1023;
    float s = b1[u] + b2[u];
#pragma unroll
    for (int dc = 0; dc < 8; ++dc) s += bpart[(size_t)(b * 8 + dc) * CU + u];
    bias[idx] = s;
}

// ---- pack W1[D][U] f32 -> bf16, MFMA-B fragment-linear tiles ----
// idx = (kt*4+ut)*8192 + ub*512 + l*8 + j ; d = kt*32 + (l>>4)*8 + j ; u = ut*256 + ub*16 + (l&15)
__global__ void k_packW1(const float* __restrict__ W1, unsigned short* __restrict__ W1p) {
    int tid = blockIdx.x * 256 + threadIdx.x;   // 131072 threads, 8 elems each
    int o8  = tid * 8;
    int l   = (o8 >> 3) & 63;
    int ub  = (o8 >> 9) & 15;
    int ut  = (o8 >> 13) & 3;
    int kt  = o8 >> 15;
    int u  = ut * 256 + ub * 16 + (l & 15);
    int d0 = kt * 32 + (l >> 4) * 8;
    ushort8 v;
#pragma unroll
    for (int j = 0; j < 8; ++j)
        v[j] = (unsigned short)f2bf_u(W1[(size_t)(d0 + j) * CU + u]);
    *(ushort8*)(W1p + o8) = v;
}

// ---- fused score GEMM v4: BM=128 x U_blk=512, 8 waves, wave tile 128r x 64c.
// Round-5 schedule (proven no-spill) with: halved B traffic per step (32 KB),
// A bf16 frag-linear LDS dbuf 2x8KB (XOR-swizzled), B global->reg dbuf,
// per-block K-phase rotation (defeats XCD-wide W1p hot-set camping in L2).
__global__ __launch_bounds__(512, 2) void k_score(
    const float* __restrict__ values, const unsigned short* __restrict__ W1p,
    const float* __restrict__ bias, const float* __restrict__ V,
    float* __restrict__ score2) {
    __shared__ __align__(16) char smem[16384];   // A dbuf 2 x 8 KB; red reuses buf0

    const int t = threadIdx.x;
    const int w = t >> 6, l = t & 63;
    const int p = blockIdx.x;                  // 1024 blocks
    const int xt = (p & 7) + (p >> 4) * 8;     // m-tile 0..511
    const int uc = (p >> 3) & 1;               // u-chunk 0..1 (pair p, p+8 share A, same XCD)
    const int ph = (p >> 3) & 31;              // K-phase rotation
    const int m0 = xt * 128;
    const int bb = m0 >> 11;                   // batch (128 divides S)

    // A stage: thread t loads values[m0 + t/4][kphys*32 + (t&3)*8 ..+8] (2 x f32x4)
    const float* aSrcT = values + (size_t)(m0 + (t >> 2)) * CD + (t & 3) * 8;
    // frag-linear bf16 write: frag = t>>6 (row>>4), slot = ((row&15)^c)|(c<<4), c = t&3
    const int aWrOff = (t >> 6) * 1024
                     + (((((t >> 2) & 15) ^ (t & 3)) | ((t & 3) << 4)) << 4);
    // read slot for lane l: ((l&15)^(l>>4)) | ((l>>4)<<4)
    const int aRdOff = ((((l & 15) ^ (l >> 4)) | ((l >> 4) << 4)) << 4);
    // B: wave w covers cols uc*512 + w*64 (4 frags); frag j, k-step kp:
    //   bBase + kp*32768 + j*512
    const unsigned short* bBase = W1p + (size_t)(uc * 2 + (w >> 2)) * 8192
                                + (w & 3) * 2048 + l * 8;

    f32x4 acc[8][4];
#pragma unroll
    for (int i = 0; i < 8; ++i)
#pragma unroll
        for (int j = 0; j < 4; ++j) acc[i][j] = f32x4{0.f, 0.f, 0.f, 0.f};

    short8 bF0[4], bF1[4];
    f32x4 s0a, s0b, s1a, s1b;

    // prologue: B(ph)->bF0 ; A(ph)->buf0 ; A(ph+1)->s1 ; barrier
    {
        const unsigned short* bs = bBase + (size_t)ph * 32768;
#pragma unroll
        for (int jj = 0; jj < 4; ++jj)
            bF0[jj] = *(const short8*)(bs + jj * 512);
        f32x4 ta = __builtin_nontemporal_load((const f32x4*)(aSrcT + ph * 32));
        f32x4 tb = __builtin_nontemporal_load((const f32x4*)(aSrcT + ph * 32 + 4));
        *(short8*)(smem + aWrOff) = cvt8(ta, tb);
        const int kp1 = (ph + 1) & 31;
        s1a = __builtin_nontemporal_load((const f32x4*)(aSrcT + kp1 * 32));
        s1b = __builtin_nontemporal_load((const f32x4*)(aSrcT + kp1 * 32 + 4));
        asm volatile("s_waitcnt lgkmcnt(0)" ::: "memory");
        asm volatile("s_barrier" ::: "memory");
    }

#define SCORE_BODY(KT, BF_CUR, BF_NXT, SLa, SLb, SWa, SWb, DO_LDB, DO_LDA, DO_WR)  \
    {                                                                               \
        if (DO_LDB) {                                                               \
            const int kp = ((KT) + 1 + ph) & 31;                                    \
            const unsigned short* bs = bBase + (size_t)kp * 32768;                  \
            _Pragma("unroll")                                                       \
            for (int jj = 0; jj < 4; ++jj)                                          \
                BF_NXT[jj] = *(const short8*)(bs + jj * 512);                       \
        }                                                                           \
        if (DO_LDA) {                                                               \
            const int kp = ((KT) + 2 + ph) & 31;                                    \
            SLa = __builtin_nontemporal_load((const f32x4*)(aSrcT + kp * 32));      \
            SLb = __builtin_nontemporal_load((const f32x4*)(aSrcT + kp * 32 + 4));  \
        }                                                                           \
        const char* aB = smem + ((KT) & 1) * 8192;                                  \
        short8 aF[8];                                                               \
        _Pragma("unroll")                                                           \
        for (int i = 0; i < 8; ++i)                                                 \
            aF[i] = *(const short8*)(aB + i * 1024 + aRdOff);                       \
        __builtin_amdgcn_s_setprio(1);                                              \
        _Pragma("unroll")                                                           \
        for (int i = 0; i < 8; ++i)                                                 \
            _Pragma("unroll")                                                       \
            for (int j = 0; j < 4; ++j)                                             \
                acc[i][j] = __builtin_amdgcn_mfma_f32_16x16x32_bf16(                \
                    aF[i], BF_CUR[j], acc[i][j], 0, 0, 0);                          \
        __builtin_amdgcn_s_setprio(0);                                              \
        if (DO_WR)                                                                  \
            *(short8*)(smem + (((KT) + 1) & 1) * 8192 + aWrOff) = cvt8(SWa, SWb);   \
        asm volatile("s_waitcnt lgkmcnt(0)" ::: "memory");                          \
        asm volatile("s_barrier" ::: "memory");                                     \
    }

    for (int kt = 0; kt < 30; kt += 2) {
        SCORE_BODY(kt,     bF0, bF1, s0a, s0b, s1a, s1b, 1, 1, 1)
        SCORE_BODY(kt + 1, bF1, bF0, s1a, s1b, s0a, s0b, 1, 1, 1)
    }
    SCORE_BODY(30, bF0, bF1, s0a, s0b, s1a, s1b, 1, 0, 1)   // B(31), write A(31)=s1
    SCORE_BODY(31, bF1, bF0, s1a, s1b, s0a, s0b, 0, 0, 0)
#undef SCORE_BODY

    // epilogue: partial over this wave's 64 cols, all 128 rows
    float part[8][4];
#pragma unroll
    for (int i = 0; i < 8; ++i)
#pragma unroll
        for (int rr = 0; rr < 4; ++rr) part[i][rr] = 0.f;

#pragma unroll
    for (int j = 0; j < 4; ++j) {
        const int col = uc * 512 + w * 64 + j * 16 + (l & 15);
        const float vv = V[col];
        const float bz = bias[bb * CU + col];
#pragma unroll
        for (int i = 0; i < 8; ++i)
#pragma unroll
            for (int rr = 0; rr < 4; ++rr)
                part[i][rr] += vv * tanh_fast(acc[i][j][rr] + bz);
    }

    float* red = (float*)smem;   // [8][128] f32 = 4 KB in buf0 area
#pragma unroll
    for (int i = 0; i < 8; ++i)
#pragma unroll
        for (int rr = 0; rr < 4; ++rr) {
            float v = part[i][rr];
            v += __shfl_xor(v, 1);
            v += __shfl_xor(v, 2);
            v += __shfl_xor(v, 4);
            v += __shfl_xor(v, 8);
            if ((l & 15) == 0)
                red[w * 128 + i * 16 + (l >> 4) * 4 + rr] = v;
        }
    __syncthreads();
    if (t < 128) {
        float sv = 0.f;
#pragma unroll
        for (int ww = 0; ww < 8; ++ww) sv += red[ww * 128 + t];
        score2[(size_t)uc * CM + m0 + t] = sv;
    }
}

// ---- softmax over S per batch; sums the 2 u-chunk slices ----
__global__ void k_softmax(const float* __restrict__ score2, float* __restrict__ wts) {
    int b = blockIdx.x, t = threadIdx.x;   // 1024 threads
    int i0 = b * CS + t, i1 = i0 + 1024;
    float s0 = score2[i0] + score2[CM + i0];
    float s1 = score2[i1] + score2[CM + i1];
    __shared__ float red[16];
    int wv = t >> 6, ln = t & 63;
    float m = fmaxf(s0, s1);
#pragma unroll
    for (int o = 32; o >= 1; o >>= 1) m = fmaxf(m, __shfl_xor(m, o));
    if (ln == 0) red[wv] = m;
    __syncthreads();
    float M = red[0];
#pragma unroll
    for (int k = 1; k < 16; ++k) M = fmaxf(M, red[k]);
    float e0 = __expf(s0 - M), e1 = __expf(s1 - M);
    float sm = e0 + e1;
#pragma unroll
    for (int o = 32; o >= 1; o >>= 1) sm += __shfl_xor(sm, o);
    __syncthreads();
    if (ln == 0) red[wv] = sm;
    __syncthreads();
    float T = 0.f;
#pragma unroll
    for (int k = 0; k < 16; ++k) T += red[k];
    float inv = 1.0f / T;
    wts[i0] = e0 * inv;
    wts[i1] = e1 * inv;
}

// ---- context ----
__global__ void k_ctx_part(const float* __restrict__ values, const float* __restrict__ wts,
                           float* __restrict__ part) {
    int b = blockIdx.y, sc = blockIdx.x;   // 32 x 32
    int t = threadIdx.x;                    // 256, float4 each -> full D
    const float* vb = values + ((size_t)b * CS + sc * 64) * CD + t * 4;
    const float* wb = wts + b * CS + sc * 64;
    f32x4 a = {0.f, 0.f, 0.f, 0.f};
#pragma unroll 8
    for (int s = 0; s < 64; ++s) {
        float wgt = wb[s];
        f32x4 v = *(const f32x4*)(vb + (size_t)s * CD);
        a += v * wgt;
    }
    *(f32x4*)(part + (size_t)(b * 32 + sc) * CD + t * 4) = a;
}

__global__ void k_ctx_red(const float* __restrict__ part, float* __restrict__ ctx) {
    int idx = blockIdx.x * 256 + threadIdx.x;   // 32768
    int b = idx >> 10, d = idx & 1023;
    float s = 0.f;
#pragma unroll 8
    for (int c = 0; c < 32; ++c) s += part[(size_t)(b * 32 + c) * CD + d];
    ctx[idx] = s;
}

extern "C" void kernel_launch(void* const* d_in, const int* in_sizes, int n_in,
                              void* d_out, int out_size, void* d_ws, size_t ws_size,
                              hipStream_t stream) {
    const float* query  = (const float*)d_in[0];
    const float* values = (const float*)d_in[1];
    const float* W1     = (const float*)d_in[2];
    const float* b1     = (const float*)d_in[3];
    const float* W2     = (const float*)d_in[4];
    const float* b2     = (const float*)d_in[5];
    const float* V      = (const float*)d_in[6];
    // d_in[7] = bV: softmax shift-invariant, score not an output -> unused

    float* out = (float*)d_out;
    float* ctx = out;            // [32][1024]
    float* wts = out + 32768;    // [32][2048]

    char* ws = (char*)d_ws;
    float*          score2 = (float*)ws;                                       // 512 KB (1 MB reserved)
    float*          bias   = (float*)(ws + (1 << 20));                         // 128 KB
    unsigned short* W1p    = (unsigned short*)(ws + (1 << 20) + (1 << 17));    // 2 MB
    float*          part   = (float*)(ws + (1 << 20) + (1 << 17) + (1 << 21)); // 4 MB
    float*          bpart  = part;   // 1 MB, consumed before k_ctx_part

    k_bias1<<<dim3(8, 32), 256, 0, stream>>>(query, W2, bpart);
    k_bias2<<<128, 256, 0, stream>>>(bpart, b1, b2, bias);
    k_packW1<<<512, 256, 0, stream>>>(W1, W1p);
    k_score<<<1024, 512, 0, stream>>>(values, W1p, bias, V, score2);
    k_softmax<<<32, 1024, 0, stream>>>(score2, wts);
    k_ctx_part<<<dim3(32, 32), 256, 0, stream>>>(values, wts, part);
    k_ctx_red<<<128, 256, 0, stream>>>(part, ctx);
}

// Round 8
// 243.836 us; speedup vs baseline: 1.5858x; 1.0172x over previous
//
#include <hip/hip_runtime.h>

#define DEVFN __device__ __forceinline__

typedef __attribute__((ext_vector_type(4))) float f32x4;
typedef __attribute__((ext_vector_type(8))) short short8;
typedef __attribute__((ext_vector_type(4))) unsigned int uint4v;
typedef __attribute__((ext_vector_type(8))) unsigned short ushort8;

constexpr int CB = 32;
constexpr int CS = 2048;
constexpr int CD = 1024;
constexpr int CU = 1024;
constexpr int CM = CB * CS;   // 65536

DEVFN unsigned f2bf_u(float f) {
    unsigned u = __float_as_uint(f);
    return (u + 0x7FFFu + ((u >> 16) & 1u)) >> 16;   // RNE f32->bf16
}
DEVFN unsigned f2bf_pack(float lo, float hi) {
    return f2bf_u(lo) | (f2bf_u(hi) << 16);
}
DEVFN short8 cvt8(f32x4 a, f32x4 b) {
    uint4v p;
    p[0] = f2bf_pack(a[0], a[1]);
    p[1] = f2bf_pack(a[2], a[3]);
    p[2] = f2bf_pack(b[0], b[1]);
    p[3] = f2bf_pack(b[2], b[3]);
    return __builtin_bit_cast(short8, p);
}
DEVFN float tanh_fast(float x) {
    float e = exp2f(x * 2.885390081777927f);
    return 1.0f - 2.0f * __builtin_amdgcn_rcpf(e + 1.0f);
}

// ---- bias = b1 + b2 + q@W2, two-stage split-D ----
__global__ void k_bias1(const float* __restrict__ q, const float* __restrict__ W2,
                        float* __restrict__ bpart) {
    int dc = blockIdx.x, b = blockIdx.y;   // 8 x 32
    int t = threadIdx.x;                    // 256
    __shared__ float qs[128];
    if (t < 128) qs[t] = q[b * CD + dc * 128 + t];
    __syncthreads();
    float acc0 = 0.f, acc1 = 0.f, acc2 = 0.f, acc3 = 0.f;
    const float* w2 = W2 + (size_t)(dc * 128) * CU + t;
#pragma unroll 4
    for (int d = 0; d < 128; ++d) {
        float qv = qs[d];
        const float* r = w2 + (size_t)d * CU;
        acc0 += qv * r[0];
        acc1 += qv * r[256];
        acc2 += qv * r[512];
        acc3 += qv * r[768];
    }
    float* o = bpart + (size_t)(b * 8 + dc) * CU + t;
    o[0] = acc0; o[256] = acc1; o[512] = acc2; o[768] = acc3;
}

__global__ void k_bias2(const float* __restrict__ bpart, const float* __restrict__ b1,
                        const float* __restrict__ b2, float* __restrict__ bias) {
    int idx = blockIdx.x * 256 + threadIdx.x;   // 32768
    int b = idx >> 10, u = idx & 1023;
    float s = b1[u] + b2[u];
#pragma unroll
    for (int dc = 0; dc < 8; ++dc) s += bpart[(size_t)(b * 8 + dc) * CU + u];
    bias[idx] = s;
}

// ---- pack W1[D][U] f32 -> bf16, MFMA-B fragment-linear tiles ----
// idx = (kt*4+ut)*8192 + ub*512 + l*8 + j ; d = kt*32 + (l>>4)*8 + j ; u = ut*256 + ub*16 + (l&15)
__global__ void k_packW1(const float* __restrict__ W1, unsigned short* __restrict__ W1p) {
    int tid = blockIdx.x * 256 + threadIdx.x;   // 131072 threads, 8 elems each
    int o8  = tid * 8;
    int l   = (o8 >> 3) & 63;
    int ub  = (o8 >> 9) & 15;
    int ut  = (o8 >> 13) & 3;
    int kt  = o8 >> 15;
    int u  = ut * 256 + ub * 16 + (l & 15);
    int d0 = kt * 32 + (l >> 4) * 8;
    ushort8 v;
#pragma unroll
    for (int j = 0; j < 8; ++j)
        v[j] = (unsigned short)f2bf_u(W1[(size_t)(d0 + j) * CU + u]);
    *(ushort8*)(W1p + o8) = v;
}

// ---- fused score GEMM v5: BM=128 x U_blk=512, 8 waves, wave tile 128r x 64c.
// Round-7 layouts/registers + TWO m201-style phases per K-step:
//   {ds_read half-A || issue loads} -> s_barrier -> setprio(1) 16xMFMA setprio(0)
// Barriers create wave role-split so setprio arbitrates (T3->T5); data waits
// stay compiler-counted (never vmcnt(0) in-loop); sched_barrier(0) pins MFMA.
__global__ __launch_bounds__(512, 2) void k_score(
    const float* __restrict__ values, const unsigned short* __restrict__ W1p,
    const float* __restrict__ bias, const float* __restrict__ V,
    float* __restrict__ score2) {
    __shared__ __align__(16) char smem[16384];   // A dbuf 2 x 8 KB; red reuses buf0

    const int t = threadIdx.x;
    const int w = t >> 6, l = t & 63;
    const int p = blockIdx.x;                  // 1024 blocks
    const int xt = (p & 7) + (p >> 4) * 8;     // m-tile 0..511
    const int uc = (p >> 3) & 1;               // u-chunk (pair p, p+8 share A rows)
    const int ph = (p >> 3) & 31;              // K-phase rotation
    const int m0 = xt * 128;
    const int bb = m0 >> 11;                   // batch (128 divides S)

    // A stage: thread t loads values[m0 + t/4][kphys*32 + (t&3)*8 ..+8] (2 x f32x4)
    const float* aSrcT = values + (size_t)(m0 + (t >> 2)) * CD + (t & 3) * 8;
    const int aWrOff = (t >> 6) * 1024
                     + (((((t >> 2) & 15) ^ (t & 3)) | ((t & 3) << 4)) << 4);
    const int aRdOff = ((((l & 15) ^ (l >> 4)) | ((l >> 4) << 4)) << 4);
    // B: wave w covers cols uc*512 + w*64 (4 frags); frag j at kp*32768 + j*512 shorts
    const unsigned short* bBase = W1p + (size_t)(uc * 2 + (w >> 2)) * 8192
                                + (w & 3) * 2048 + l * 8;

    f32x4 acc[8][4];
#pragma unroll
    for (int i = 0; i < 8; ++i)
#pragma unroll
        for (int j = 0; j < 4; ++j) acc[i][j] = f32x4{0.f, 0.f, 0.f, 0.f};

    short8 bF0[4], bF1[4];
    f32x4 s0a, s0b, s1a, s1b;

    // prologue: B(ph)->bF0 ; A(ph)->buf0 ; A(ph+1)->s1 ; barrier
    {
        const unsigned short* bs = bBase + (size_t)ph * 32768;
#pragma unroll
        for (int jj = 0; jj < 4; ++jj)
            bF0[jj] = *(const short8*)(bs + jj * 512);
        f32x4 ta = __builtin_nontemporal_load((const f32x4*)(aSrcT + ph * 32));
        f32x4 tb = __builtin_nontemporal_load((const f32x4*)(aSrcT + ph * 32 + 4));
        *(short8*)(smem + aWrOff) = cvt8(ta, tb);
        const int kp1 = (ph + 1) & 31;
        s1a = __builtin_nontemporal_load((const f32x4*)(aSrcT + kp1 * 32));
        s1b = __builtin_nontemporal_load((const f32x4*)(aSrcT + kp1 * 32 + 4));
        asm volatile("s_waitcnt lgkmcnt(0)" ::: "memory");
        asm volatile("s_barrier" ::: "memory");
    }

#define SCORE_BODY(KT, BF_CUR, BF_NXT, SLa, SLb, SWa, SWb, DO_LDB, DO_LDA, DO_WR)  \
    {                                                                               \
        const char* aB = smem + ((KT) & 1) * 8192;                                  \
        /* ---------------- phase 0: rows 0..63 ---------------- */                 \
        {                                                                           \
            short8 aF[4];                                                           \
            _Pragma("unroll")                                                       \
            for (int i = 0; i < 4; ++i)                                             \
                aF[i] = *(const short8*)(aB + i * 1024 + aRdOff);                   \
            if (DO_LDB) {                                                           \
                const int kp = ((KT) + 1 + ph) & 31;                                \
                const unsigned short* bs = bBase + (size_t)kp * 32768;              \
                BF_NXT[0] = *(const short8*)(bs);                                   \
                BF_NXT[1] = *(const short8*)(bs + 512);                             \
            }                                                                       \
            __builtin_amdgcn_sched_barrier(0);                                      \
            asm volatile("s_barrier" ::: "memory");                                 \
            __builtin_amdgcn_sched_barrier(0);                                      \
            __builtin_amdgcn_s_setprio(1);                                          \
            _Pragma("unroll")                                                       \
            for (int i = 0; i < 4; ++i)                                             \
                _Pragma("unroll")                                                   \
                for (int j = 0; j < 4; ++j)                                         \
                    acc[i][j] = __builtin_amdgcn_mfma_f32_16x16x32_bf16(            \
                        aF[i], BF_CUR[j], acc[i][j], 0, 0, 0);                      \
            __builtin_amdgcn_s_setprio(0);                                          \
            __builtin_amdgcn_sched_barrier(0);                                      \
        }                                                                           \
        /* ---------------- phase 1: rows 64..127 ---------------- */               \
        {                                                                           \
            short8 aF[4];                                                           \
            _Pragma("unroll")                                                       \
            for (int i = 0; i < 4; ++i)                                             \
                aF[i] = *(const short8*)(aB + (i + 4) * 1024 + aRdOff);             \
            if (DO_LDB) {                                                           \
                const int kp = ((KT) + 1 + ph) & 31;                                \
                const unsigned short* bs = bBase + (size_t)kp * 32768;              \
                BF_NXT[2] = *(const short8*)(bs + 1024);                            \
                BF_NXT[3] = *(const short8*)(bs + 1536);                            \
            }                                                                       \
            if (DO_LDA) {                                                           \
                const int kp = ((KT) + 2 + ph) & 31;                                \
                SLa = __builtin_nontemporal_load((const f32x4*)(aSrcT + kp * 32));  \
                SLb = __builtin_nontemporal_load((const f32x4*)(aSrcT + kp * 32 + 4)); \
            }                                                                       \
            if (DO_WR)                                                              \
                *(short8*)(smem + (((KT) + 1) & 1) * 8192 + aWrOff) = cvt8(SWa, SWb); \
            asm volatile("s_waitcnt lgkmcnt(0)" ::: "memory");                      \
            __builtin_amdgcn_sched_barrier(0);                                      \
            asm volatile("s_barrier" ::: "memory");                                 \
            __builtin_amdgcn_sched_barrier(0);                                      \
            __builtin_amdgcn_s_setprio(1);                                          \
            _Pragma("unroll")                                                       \
            for (int i = 0; i < 4; ++i)                                             \
                _Pragma("unroll")                                                   \
                for (int j = 0; j < 4; ++j)                                         \
                    acc[i + 4][j] = __builtin_amdgcn_mfma_f32_16x16x32_bf16(        \
                        aF[i], BF_CUR[j], acc[i + 4][j], 0, 0, 0);                  \
            __builtin_amdgcn_s_setprio(0);                                          \
            __builtin_amdgcn_sched_barrier(0);                                      \
        }                                                                           \
    }

    for (int kt = 0; kt < 30; kt += 2) {
        SCORE_BODY(kt,     bF0, bF1, s0a, s0b, s1a, s1b, 1, 1, 1)
        SCORE_BODY(kt + 1, bF1, bF0, s1a, s1b, s0a, s0b, 1, 1, 1)
    }
    SCORE_BODY(30, bF0, bF1, s0a, s0b, s1a, s1b, 1, 0, 1)   // B(31), write A(31)=s1
    SCORE_BODY(31, bF1, bF0, s1a, s1b, s0a, s0b, 0, 0, 0)
#undef SCORE_BODY

    // epilogue: partial over this wave's 64 cols, all 128 rows
    float part[8][4];
#pragma unroll
    for (int i = 0; i < 8; ++i)
#pragma unroll
        for (int rr = 0; rr < 4; ++rr) part[i][rr] = 0.f;

#pragma unroll
    for (int j = 0; j < 4; ++j) {
        const int col = uc * 512 + w * 64 + j * 16 + (l & 15);
        const float vv = V[col];
        const float bz = bias[bb * CU + col];
#pragma unroll
        for (int i = 0; i < 8; ++i)
#pragma unroll
            for (int rr = 0; rr < 4; ++rr)
                part[i][rr] += vv * tanh_fast(acc[i][j][rr] + bz);
    }

    float* red = (float*)smem;   // [8][128] f32 = 4 KB in buf0 area
#pragma unroll
    for (int i = 0; i < 8; ++i)
#pragma unroll
        for (int rr = 0; rr < 4; ++rr) {
            float v = part[i][rr];
            v += __shfl_xor(v, 1);
            v += __shfl_xor(v, 2);
            v += __shfl_xor(v, 4);
            v += __shfl_xor(v, 8);
            if ((l & 15) == 0)
                red[w * 128 + i * 16 + (l >> 4) * 4 + rr] = v;
        }
    __syncthreads();
    if (t < 128) {
        float sv = 0.f;
#pragma unroll
        for (int ww = 0; ww < 8; ++ww) sv += red[ww * 128 + t];
        score2[(size_t)uc * CM + m0 + t] = sv;
    }
}

// ---- softmax over S per batch; sums the 2 u-chunk slices ----
__global__ void k_softmax(const float* __restrict__ score2, float* __restrict__ wts) {
    int b = blockIdx.x, t = threadIdx.x;   // 1024 threads
    int i0 = b * CS + t, i1 = i0 + 1024;
    float s0 = score2[i0] + score2[CM + i0];
    float s1 = score2[i1] + score2[CM + i1];
    __shared__ float red[16];
    int wv = t >> 6, ln = t & 63;
    float m = fmaxf(s0, s1);
#pragma unroll
    for (int o = 32; o >= 1; o >>= 1) m = fmaxf(m, __shfl_xor(m, o));
    if (ln == 0) red[wv] = m;
    __syncthreads();
    float M = red[0];
#pragma unroll
    for (int k = 1; k < 16; ++k) M = fmaxf(M, red[k]);
    float e0 = __expf(s0 - M), e1 = __expf(s1 - M);
    float sm = e0 + e1;
#pragma unroll
    for (int o = 32; o >= 1; o >>= 1) sm += __shfl_xor(sm, o);
    __syncthreads();
    if (ln == 0) red[wv] = sm;
    __syncthreads();
    float T = 0.f;
#pragma unroll
    for (int k = 0; k < 16; ++k) T += red[k];
    float inv = 1.0f / T;
    wts[i0] = e0 * inv;
    wts[i1] = e1 * inv;
}

// ---- context ----
__global__ void k_ctx_part(const float* __restrict__ values, const float* __restrict__ wts,
                           float* __restrict__ part) {
    int b = blockIdx.y, sc = blockIdx.x;   // 32 x 32
    int t = threadIdx.x;                    // 256, float4 each -> full D
    const float* vb = values + ((size_t)b * CS + sc * 64) * CD + t * 4;
    const float* wb = wts + b * CS + sc * 64;
    f32x4 a = {0.f, 0.f, 0.f, 0.f};
#pragma unroll 8
    for (int s = 0; s < 64; ++s) {
        float wgt = wb[s];
        f32x4 v = *(const f32x4*)(vb + (size_t)s * CD);
        a += v * wgt;
    }
    *(f32x4*)(part + (size_t)(b * 32 + sc) * CD + t * 4) = a;
}

__global__ void k_ctx_red(const float* __restrict__ part, float* __restrict__ ctx) {
    int idx = blockIdx.x * 256 + threadIdx.x;   // 32768
    int b = idx >> 10, d = idx & 1023;
    float s = 0.f;
#pragma unroll 8
    for (int c = 0; c < 32; ++c) s += part[(size_t)(b * 32 + c) * CD + d];
    ctx[idx] = s;
}

extern "C" void kernel_launch(void* const* d_in, const int* in_sizes, int n_in,
                              void* d_out, int out_size, void* d_ws, size_t ws_size,
                              hipStream_t stream) {
    const float* query  = (const float*)d_in[0];
    const float* values = (const float*)d_in[1];
    const float* W1     = (const float*)d_in[2];
    const float* b1     = (const float*)d_in[3];
    const float* W2     = (const float*)d_in[4];
    const float* b2     = (const float*)d_in[5];
    const float* V      = (const float*)d_in[6];
    // d_in[7] = bV: softmax shift-invariant, score not an output -> unused

    float* out = (float*)d_out;
    float* ctx = out;            // [32][1024]
    float* wts = out + 32768;    // [32][2048]

    char* ws = (char*)d_ws;
    float*          score2 = (float*)ws;                                       // 512 KB (1 MB reserved)
    float*          bias   = (float*)(ws + (1 << 20));                         // 128 KB
    unsigned short* W1p    = (unsigned short*)(ws + (1 << 20) + (1 << 17));    // 2 MB
    float*          part   = (float*)(ws + (1 << 20) + (1 << 17) + (1 << 21)); // 4 MB
    float*          bpart  = part;   // 1 MB, consumed before k_ctx_part

    k_bias1<<<dim3(8, 32), 256, 0, stream>>>(query, W2, bpart);
    k_bias2<<<128, 256, 0, stream>>>(bpart, b1, b2, bias);
    k_packW1<<<512, 256, 0, stream>>>(W1, W1p);
    k_score<<<1024, 512, 0, stream>>>(values, W1p, bias, V, score2);
    k_softmax<<<32, 1024, 0, stream>>>(score2, wts);
    k_ctx_part<<<dim3(32, 32), 256, 0, stream>>>(values, wts, part);
    k_ctx_red<<<128, 256, 0, stream>>>(part, ctx);
}